// Round 1
// 2395.420 us; speedup vs baseline: 1.4844x; 1.4844x over previous
//
#include <hip/hip_runtime.h>

#define BB 32
#define TT 512
#define INW 256
#define HH 1024
#define OUTW 256
#define SLOT 32768  // ushorts per ring slot; layout [64 chunks][32 b][16 j]
// 3H = 3072

typedef __attribute__((ext_vector_type(8))) short short8;
typedef __attribute__((ext_vector_type(4))) float floatx4;

// LDS reduce swizzle: XOR dword-index bits 2-3 with (source-lane bits 3-4).
// Write side: idx bits 5-6 come from lane*4 -> lane bits 3-4. Read side: idx
// bits 5-6 come from rl*4 -> rl bits 3-4 (rl == producing lane). Spreads the
// reduce's scalar reads from 16 banks/4-way to 32 banks/2-way (free).
#define RSWZ(i) ((i) ^ ((((i) >> 5) & 3) << 2))

__device__ __forceinline__ unsigned short f2bf(float f) {
    unsigned int u = __float_as_uint(f);
    u = (u + 0x7fffu + ((u >> 16) & 1u)) >> 16;
    return (unsigned short)u;
}
__device__ __forceinline__ float bf2f(unsigned short h) {
    return __uint_as_float(((unsigned int)h) << 16);
}
__device__ __forceinline__ float fast_tanh(float x) {
    // 2/(1+e^-2x)-1: exact saturation at +/-inf, err ~1e-6 << bf16 quantum
    return 2.f / (1.f + __expf(-2.f * x)) - 1.f;
}

__global__ void cast_f32_bf16(const float* __restrict__ src,
                              unsigned short* __restrict__ dst, int n) {
    int i = blockIdx.x * blockDim.x + threadIdx.x;
    int stride = gridDim.x * blockDim.x;
    for (; i < n; i += stride) dst[i] = f2bf(src[i]);
}

// C_bf16[M x 3072] = X_bf16[M x K] @ W_bf16[3072 x K]^T + bias_f32
template <int K>
__global__ __launch_bounds__(256) void gemm_gx(const unsigned short* __restrict__ X,
                                               const unsigned short* __restrict__ W,
                                               const float* __restrict__ bias,
                                               unsigned short* __restrict__ Cout) {
    __shared__ __align__(16) unsigned short As[64 * 40];
    __shared__ __align__(16) unsigned short Bs[64 * 40];
    int bid = blockIdx.x;
    int tn = bid % 48, tm = bid / 48;
    int tid = threadIdx.x;
    int lane = tid & 63, wv = tid >> 6;
    int wm = wv >> 1, wn = wv & 1;
    int l15 = lane & 15, q = lane >> 4;
    floatx4 acc[2][2] = {};
    int r = tid >> 2, kq = (tid & 3) * 8;
    const unsigned short* xrow = X + (size_t)(tm * 64 + r) * K;
    const unsigned short* wrow = W + (size_t)(tn * 64 + r) * K;
    const int NK = K / 32;
    for (int kk = 0; kk < NK; ++kk) {
        int k0 = kk * 32;
        *(short8*)&As[r * 40 + kq] = *(const short8*)&xrow[k0 + kq];
        *(short8*)&Bs[r * 40 + kq] = *(const short8*)&wrow[k0 + kq];
        __syncthreads();
        short8 a0 = *(const short8*)&As[(wm * 32 + l15) * 40 + q * 8];
        short8 a1 = *(const short8*)&As[(wm * 32 + 16 + l15) * 40 + q * 8];
        short8 b0 = *(const short8*)&Bs[(wn * 32 + l15) * 40 + q * 8];
        short8 b1 = *(const short8*)&Bs[(wn * 32 + 16 + l15) * 40 + q * 8];
        acc[0][0] = __builtin_amdgcn_mfma_f32_16x16x32_bf16(a0, b0, acc[0][0], 0, 0, 0);
        acc[0][1] = __builtin_amdgcn_mfma_f32_16x16x32_bf16(a0, b1, acc[0][1], 0, 0, 0);
        acc[1][0] = __builtin_amdgcn_mfma_f32_16x16x32_bf16(a1, b0, acc[1][0], 0, 0, 0);
        acc[1][1] = __builtin_amdgcn_mfma_f32_16x16x32_bf16(a1, b1, acc[1][1], 0, 0, 0);
        __syncthreads();
    }
    for (int mi = 0; mi < 2; ++mi)
        for (int ni = 0; ni < 2; ++ni) {
            int col = tn * 64 + wn * 32 + ni * 16 + l15;
            float bv = bias[col];
            int row0 = tm * 64 + wm * 32 + mi * 16 + q * 4;
            for (int rr = 0; rr < 4; ++rr) {
                Cout[(size_t)(row0 + rr) * 3072 + col] = f2bf(acc[mi][ni][rr] + bv);
            }
        }
}

// Fused 2-layer persistent GRU, 128 blocks x 512 threads (8 waves).
// R11: (a) 8x replicated flag arrays, 1KB-strided, so poll traffic spreads
// across L3 channels instead of funneling 192 polling waves into 4 cache
// lines (theory: the ~10k cyc/step flag-wait is L3 line queueing, not the
// handoff floor). Producers post to all 8 replicas (lane-parallel, wave 0);
// consumer polls replica (bid&7). (b) LDS RSWZ swizzle on the reduce buffer
// (4-way -> conflict-free). (c) ring a-fragment loads hoisted ahead of the
// MFMA chain (single latency exposure). (d) fast_tanh replaces tanhf.
// Flags layout (dwords): L0 replicas r=0..7 at r*256 + bid; L1 replicas at
// 2048 + r*256 + b2. Monotone step counters, write-once rings, agent-scope
// store + vmcnt drain + flag release as before.
__global__ __launch_bounds__(512, 2) void gru_fused(
    const unsigned short* __restrict__ gx0, const unsigned short* __restrict__ whh0,
    const float* __restrict__ bhh0, const unsigned short* __restrict__ wih1,
    const unsigned short* __restrict__ whh1, const float* __restrict__ bih1,
    const float* __restrict__ bhh1, unsigned short* __restrict__ ring0,
    unsigned short* __restrict__ ring1, float* __restrict__ hn0,
    float* __restrict__ hn1, unsigned int* __restrict__ flags) {
    __shared__ __align__(16) float red[8 * 6 * 64 * 4];  // 48 KB
    const int bid = blockIdx.x;
    const int tid = threadIdx.x;
    const int lane = tid & 63, wv = tid >> 6;
    const int l15 = lane & 15, q = lane >> 4;
    const int gb = tid >> 3, gjh = tid & 7;
    const int gmi = gb >> 4, greg = gb & 3;
    const int grl = ((gb & 15) >> 2) * 16 + 2 * gjh;  // MFMA C-layout lane (i=0)

    if (bid < 64) {
        // ================= layer 0 : 8-way K-split, K=128/wave =================
        const int j0 = bid * 16;
        const int kbase = wv * 128;
        const unsigned int* fl0 = flags + ((bid & 7) << 8);  // own replica
        short8 Wr[4], Wz[4], Wn[4];
        {
            const unsigned short* wr0 = whh0 + (size_t)(j0 + l15) * HH;
            const unsigned short* wr1 = whh0 + (size_t)(1024 + j0 + l15) * HH;
            const unsigned short* wr2 = whh0 + (size_t)(2048 + j0 + l15) * HH;
#pragma unroll
            for (int s = 0; s < 4; ++s) {
                int k = kbase + s * 32 + q * 8;
                Wr[s] = *(const short8*)&wr0[k];
                Wz[s] = *(const short8*)&wr1[k];
                Wn[s] = *(const short8*)&wr2[k];
            }
        }
        float bR[2], bZ[2], bN[2], hpriv[2] = {0.f, 0.f};
        unsigned int pxr = 0, pxz = 0, pxn = 0;
        const unsigned short* gxp = nullptr;
        if (tid < 256) {
            int jj = j0 + 2 * gjh;
#pragma unroll
            for (int i = 0; i < 2; ++i) {
                bR[i] = bhh0[jj + i];
                bZ[i] = bhh0[1024 + jj + i];
                bN[i] = bhh0[2048 + jj + i];
            }
            gxp = gx0 + (size_t)gb * TT * 3072 + jj;
            pxr = *(const unsigned int*)(gxp);
            pxz = *(const unsigned int*)(gxp + 1024);
            pxn = *(const unsigned int*)(gxp + 2048);
        }

        for (int t = 0; t < TT; ++t) {
            if (t > 0 && wv == 0) {
                unsigned int target = (unsigned int)t;
                while (true) {
                    unsigned int v = __hip_atomic_load(fl0 + lane, __ATOMIC_RELAXED,
                                                       __HIP_MEMORY_SCOPE_AGENT);
                    if (__all((int)(v >= target))) break;
                    __builtin_amdgcn_s_sleep(1);
                }
            }
            __syncthreads();
            const unsigned short* hc = ring0 + (size_t)t * SLOT;
            unsigned int cxr = pxr, cxz = pxz, cxn = pxn;

            // hoisted a-fragment loads (all in flight before any MFMA waits)
            short8 A0[4], A1[4];
#pragma unroll
            for (int s = 0; s < 4; ++s) {
                int k = kbase + s * 32 + q * 8;
                int cb = (k >> 4) << 9, ko = k & 15;
                A0[s] = *(const short8*)&hc[cb + (l15 << 4) + ko];
                A1[s] = *(const short8*)&hc[cb + ((16 + l15) << 4) + ko];
            }
            floatx4 acc[6] = {};
#pragma unroll
            for (int s = 0; s < 4; ++s) {
                acc[0] = __builtin_amdgcn_mfma_f32_16x16x32_bf16(A0[s], Wr[s], acc[0], 0, 0, 0);
                acc[1] = __builtin_amdgcn_mfma_f32_16x16x32_bf16(A0[s], Wz[s], acc[1], 0, 0, 0);
                acc[2] = __builtin_amdgcn_mfma_f32_16x16x32_bf16(A0[s], Wn[s], acc[2], 0, 0, 0);
                acc[3] = __builtin_amdgcn_mfma_f32_16x16x32_bf16(A1[s], Wr[s], acc[3], 0, 0, 0);
                acc[4] = __builtin_amdgcn_mfma_f32_16x16x32_bf16(A1[s], Wz[s], acc[4], 0, 0, 0);
                acc[5] = __builtin_amdgcn_mfma_f32_16x16x32_bf16(A1[s], Wn[s], acc[5], 0, 0, 0);
            }
#pragma unroll
            for (int tl = 0; tl < 6; ++tl)
                *(floatx4*)&red[RSWZ(((wv * 6 + tl) * 64 + lane) * 4)] = acc[tl];
            __syncthreads();

            float hnew[2];
            if (tid < 256) {
#pragma unroll
                for (int i = 0; i < 2; ++i) {
                    int rl = grl + i;
                    float gr = 0.f, gz = 0.f, gn = 0.f;
#pragma unroll
                    for (int w = 0; w < 8; ++w) {
                        gr += red[RSWZ(((w * 6 + gmi * 3 + 0) * 64 + rl) * 4 + greg)];
                        gz += red[RSWZ(((w * 6 + gmi * 3 + 1) * 64 + rl) * 4 + greg)];
                        gn += red[RSWZ(((w * 6 + gmi * 3 + 2) * 64 + rl) * 4 + greg)];
                    }
                    float xr = bf2f((unsigned short)(i ? (cxr >> 16) : (cxr & 0xffffu)));
                    float xz = bf2f((unsigned short)(i ? (cxz >> 16) : (cxz & 0xffffu)));
                    float xn = bf2f((unsigned short)(i ? (cxn >> 16) : (cxn & 0xffffu)));
                    float rg = 1.f / (1.f + __expf(-(xr + gr + bR[i])));
                    float zg = 1.f / (1.f + __expf(-(xz + gz + bZ[i])));
                    float ng = fast_tanh(xn + rg * (gn + bN[i]));
                    hnew[i] = (1.f - zg) * ng + zg * hpriv[i];
                    hpriv[i] = hnew[i];
                }
                unsigned int hpack =
                    (unsigned int)f2bf(hnew[0]) | ((unsigned int)f2bf(hnew[1]) << 16);
                unsigned int* dst =
                    (unsigned int*)(ring0 + (size_t)(t + 1) * SLOT) + (bid << 8) + tid;
                __hip_atomic_store(dst, hpack, __ATOMIC_RELAXED,
                                   __HIP_MEMORY_SCOPE_AGENT);
                asm volatile("s_waitcnt vmcnt(0)" ::: "memory");
            }
            __syncthreads();
            if (tid < 8)  // post to all 8 replicas, lane-parallel
                __hip_atomic_store(flags + (tid << 8) + bid, (unsigned int)(t + 1),
                                   __ATOMIC_RELAXED, __HIP_MEMORY_SCOPE_AGENT);
            if (tid < 256) {
                if (t == TT - 1) {
                    hn0[gb * HH + j0 + 2 * gjh] = hnew[0];
                    hn0[gb * HH + j0 + 2 * gjh + 1] = hnew[1];
                }
                if (t + 1 < TT) {
                    const unsigned short* g2 = gxp + (size_t)(t + 1) * 3072;
                    pxr = *(const unsigned int*)(g2);
                    pxz = *(const unsigned int*)(g2 + 1024);
                    pxn = *(const unsigned int*)(g2 + 2048);
                }
            }
        }
    } else {
        // ===== layer 1 : wave-specialized (waves 0-3 h / whh1, 4-7 x / wih1) =====
        const int b2 = bid - 64;
        const int j0 = b2 * 16;
        const bool isx = (wv >= 4);
        const int kbase = (wv & 3) * 256;
        const unsigned int* fl1 = flags + 2048 + ((b2 & 7) << 8);  // own-layer replica
        const unsigned int* fl0 = flags + ((b2 & 7) << 8);         // L0 replica
        short8 Wr[8], Wz[8], Wn[8];
        {
            const unsigned short* wsrc = isx ? wih1 : whh1;
            const unsigned short* w0 = wsrc + (size_t)(j0 + l15) * HH;
            const unsigned short* w1 = wsrc + (size_t)(1024 + j0 + l15) * HH;
            const unsigned short* w2 = wsrc + (size_t)(2048 + j0 + l15) * HH;
#pragma unroll
            for (int s = 0; s < 8; ++s) {
                int k = kbase + s * 32 + q * 8;
                Wr[s] = *(const short8*)&w0[k];
                Wz[s] = *(const short8*)&w1[k];
                Wn[s] = *(const short8*)&w2[k];
            }
        }
        float cR[2], cZ[2], cNx[2], cNh[2], hpriv[2] = {0.f, 0.f};
        if (tid < 256) {
            int jj = j0 + 2 * gjh;
#pragma unroll
            for (int i = 0; i < 2; ++i) {
                cR[i] = bih1[jj + i] + bhh1[jj + i];
                cZ[i] = bih1[1024 + jj + i] + bhh1[1024 + jj + i];
                cNx[i] = bih1[2048 + jj + i];
                cNh[i] = bhh1[2048 + jj + i];
            }
        }

        for (int t = 0; t < TT; ++t) {
            if (t > 0 && wv == 0) {  // own-layer flags (ring1 critical path)
                unsigned int target = (unsigned int)t;
                while (true) {
                    unsigned int v = __hip_atomic_load(fl1 + lane, __ATOMIC_RELAXED,
                                                       __HIP_MEMORY_SCOPE_AGENT);
                    if (__all((int)(v >= target))) break;
                    __builtin_amdgcn_s_sleep(1);
                }
            }
            if (wv == 4) {  // L0 flags for h0(t) = ring0 slot t+1 (runs ahead)
                unsigned int target = (unsigned int)(t + 1);
                while (true) {
                    unsigned int v = __hip_atomic_load(fl0 + lane, __ATOMIC_RELAXED,
                                                       __HIP_MEMORY_SCOPE_AGENT);
                    if (__all((int)(v >= target))) break;
                    __builtin_amdgcn_s_sleep(1);
                }
            }
            __syncthreads();
            const unsigned short* src =
                isx ? (ring0 + (size_t)(t + 1) * SLOT) : (ring1 + (size_t)t * SLOT);

            // hoisted a-fragment loads
            short8 A0[8], A1[8];
#pragma unroll
            for (int s = 0; s < 8; ++s) {
                int k = kbase + s * 32 + q * 8;
                int cb = (k >> 4) << 9, ko = k & 15;
                A0[s] = *(const short8*)&src[cb + (l15 << 4) + ko];
                A1[s] = *(const short8*)&src[cb + ((16 + l15) << 4) + ko];
            }
            floatx4 acc[6] = {};
#pragma unroll
            for (int s = 0; s < 8; ++s) {
                acc[0] = __builtin_amdgcn_mfma_f32_16x16x32_bf16(A0[s], Wr[s], acc[0], 0, 0, 0);
                acc[1] = __builtin_amdgcn_mfma_f32_16x16x32_bf16(A0[s], Wz[s], acc[1], 0, 0, 0);
                acc[2] = __builtin_amdgcn_mfma_f32_16x16x32_bf16(A0[s], Wn[s], acc[2], 0, 0, 0);
                acc[3] = __builtin_amdgcn_mfma_f32_16x16x32_bf16(A1[s], Wr[s], acc[3], 0, 0, 0);
                acc[4] = __builtin_amdgcn_mfma_f32_16x16x32_bf16(A1[s], Wz[s], acc[4], 0, 0, 0);
                acc[5] = __builtin_amdgcn_mfma_f32_16x16x32_bf16(A1[s], Wn[s], acc[5], 0, 0, 0);
            }
#pragma unroll
            for (int tl = 0; tl < 6; ++tl)
                *(floatx4*)&red[RSWZ(((wv * 6 + tl) * 64 + lane) * 4)] = acc[tl];
            __syncthreads();

            float hnew[2];
            if (tid < 256) {
#pragma unroll
                for (int i = 0; i < 2; ++i) {
                    int rl = grl + i;
                    float gr = 0.f, gz = 0.f, hn = 0.f, xn = 0.f;
#pragma unroll
                    for (int w = 0; w < 4; ++w) {
                        gr += red[RSWZ(((w * 6 + gmi * 3 + 0) * 64 + rl) * 4 + greg)];
                        gz += red[RSWZ(((w * 6 + gmi * 3 + 1) * 64 + rl) * 4 + greg)];
                        hn += red[RSWZ(((w * 6 + gmi * 3 + 2) * 64 + rl) * 4 + greg)];
                    }
#pragma unroll
                    for (int w = 4; w < 8; ++w) {
                        gr += red[RSWZ(((w * 6 + gmi * 3 + 0) * 64 + rl) * 4 + greg)];
                        gz += red[RSWZ(((w * 6 + gmi * 3 + 1) * 64 + rl) * 4 + greg)];
                        xn += red[RSWZ(((w * 6 + gmi * 3 + 2) * 64 + rl) * 4 + greg)];
                    }
                    float rg = 1.f / (1.f + __expf(-(gr + cR[i])));
                    float zg = 1.f / (1.f + __expf(-(gz + cZ[i])));
                    float ng = fast_tanh(xn + cNx[i] + rg * (hn + cNh[i]));
                    hnew[i] = (1.f - zg) * ng + zg * hpriv[i];
                    hpriv[i] = hnew[i];
                }
                unsigned int hpack =
                    (unsigned int)f2bf(hnew[0]) | ((unsigned int)f2bf(hnew[1]) << 16);
                unsigned int* dst =
                    (unsigned int*)(ring1 + (size_t)(t + 1) * SLOT) + (b2 << 8) + tid;
                __hip_atomic_store(dst, hpack, __ATOMIC_RELAXED,
                                   __HIP_MEMORY_SCOPE_AGENT);
                asm volatile("s_waitcnt vmcnt(0)" ::: "memory");
            }
            __syncthreads();
            if (tid < 8)  // post to all 8 L1 replicas
                __hip_atomic_store(flags + 2048 + (tid << 8) + b2, (unsigned int)(t + 1),
                                   __ATOMIC_RELAXED, __HIP_MEMORY_SCOPE_AGENT);
            if (tid < 256 && t == TT - 1) {
                hn1[gb * HH + j0 + 2 * gjh] = hnew[0];
                hn1[gb * HH + j0 + 2 * gjh + 1] = hnew[1];
            }
        }
    }
}

// h1bf is ring1 slot TT in chunked layout: (b,k) at (k>>4)*512 + b*16 + (k&15)
__global__ void fc_out(const unsigned short* __restrict__ h1bf,
                       const float* __restrict__ fcw, const float* __restrict__ fcb,
                       float* __restrict__ out) {
    int b = blockIdx.x, o = threadIdx.x;  // 32 x 256
    const float* wr = fcw + (size_t)o * HH;
    float acc = fcb[o];
    for (int k = 0; k < HH; k += 16) {
        const unsigned short* hp = h1bf + ((k >> 4) << 9) + (b << 4);
#pragma unroll
        for (int i = 0; i < 16; ++i) acc += bf2f(hp[i]) * wr[k + i];
    }
    out[b * OUTW + o] = 1.f / (1.f + expf(-acc));
}

extern "C" void kernel_launch(void* const* d_in, const int* in_sizes, int n_in,
                              void* d_out, int out_size, void* d_ws, size_t ws_size,
                              hipStream_t stream) {
    (void)in_sizes; (void)n_in; (void)out_size; (void)ws_size;
    const float* input = (const float*)d_in[0];
    const float* w_ih0 = (const float*)d_in[1];
    const float* w_hh0 = (const float*)d_in[2];
    const float* b_ih0 = (const float*)d_in[3];
    const float* b_hh0 = (const float*)d_in[4];
    const float* w_ih1 = (const float*)d_in[5];
    const float* w_hh1 = (const float*)d_in[6];
    const float* b_ih1 = (const float*)d_in[7];
    const float* b_hh1 = (const float*)d_in[8];
    const float* fc_w = (const float*)d_in[9];
    const float* fc_b = (const float*)d_in[10];
    float* out = (float*)d_out;

    char* ws = (char*)d_ws;
    size_t off = 0;
    auto alloc = [&](size_t bytes) {
        void* p = ws + off;
        off += (bytes + 255) & ~(size_t)255;
        return p;
    };
    // flags: L0 replicas r=0..7 at dword r*256+bid; L1 at 2048+r*256+b2. 16 KB.
    unsigned int* flags = (unsigned int*)alloc(16384);
    unsigned short* ring0 = (unsigned short*)alloc((size_t)(TT + 1) * SLOT * 2);
    unsigned short* ring1 = (unsigned short*)alloc((size_t)(TT + 1) * SLOT * 2);
    unsigned short* gx0 = (unsigned short*)alloc((size_t)16384 * 3072 * 2);
    unsigned short* in_bf = (unsigned short*)alloc((size_t)16384 * 256 * 2);
    unsigned short* wih0_bf = (unsigned short*)alloc((size_t)3072 * 256 * 2);
    unsigned short* whh0_bf = (unsigned short*)alloc((size_t)3072 * 1024 * 2);
    unsigned short* wih1_bf = (unsigned short*)alloc((size_t)3072 * 1024 * 2);
    unsigned short* whh1_bf = (unsigned short*)alloc((size_t)3072 * 1024 * 2);

    cast_f32_bf16<<<256, 256, 0, stream>>>(input, in_bf, 16384 * 256);
    cast_f32_bf16<<<64, 256, 0, stream>>>(w_ih0, wih0_bf, 3072 * 256);
    cast_f32_bf16<<<256, 256, 0, stream>>>(w_hh0, whh0_bf, 3072 * 1024);
    cast_f32_bf16<<<256, 256, 0, stream>>>(w_ih1, wih1_bf, 3072 * 1024);
    cast_f32_bf16<<<256, 256, 0, stream>>>(w_hh1, whh1_bf, 3072 * 1024);

    hipMemsetAsync(flags, 0, 16384, stream);
    hipMemsetAsync(ring0, 0, (size_t)SLOT * 2, stream);  // h0(0) = 0
    hipMemsetAsync(ring1, 0, (size_t)SLOT * 2, stream);  // h1(0) = 0

    // gx0 = input @ w_ih0^T + b_ih0 (layer-1 projections fused into gru kernel)
    gemm_gx<256><<<12288, 256, 0, stream>>>(in_bf, wih0_bf, b_ih0, gx0);

    gru_fused<<<128, 512, 0, stream>>>(gx0, whh0_bf, b_hh0, wih1_bf, whh1_bf, b_ih1,
                                       b_hh1, ring0, ring1, out + 8192,
                                       out + 8192 + 32768, flags);

    // ---- FC + sigmoid on h_last of layer 1 (ring1 slot TT, chunked) ----
    fc_out<<<32, 256, 0, stream>>>(ring1 + (size_t)TT * SLOT, fc_w, fc_b, out);
}